// Round 3
// baseline (930.828 us; speedup 1.0000x reference)
//
#include <hip/hip_runtime.h>

constexpr int B = 16, C = 256, O = 256, H = 128, W = 128, K = 3;
constexpr int GROUPS = 32;
constexpr int CPG = C / GROUPS;   // 8 input channels per group
constexpr int OPG = O / GROUPS;   // 8 output channels per group
constexpr int HW = H * W;         // 16384
constexpr float EPS = 1e-7f;

constexpr int NT = 512;
constexpr int TW = 64, TH = 32;   // tile: 64 wide x 32 tall, 2048 px = 512 thr x 4 px
constexpr int HALOW = TW + 2;     // 66
constexpr int HALOH = TH + 2;     // 34
// XSTR=72: 72%4==0 (16B-aligned rows); 72 mod 32 = 8 -> b128 phase groups of 8
// lanes cover 32 distinct banks (same conflict-free structure as XSTR=40).
constexpr int XSTR = 72;
constexpr int SELEM = HALOH * HALOW;  // 2244 staged elems per plane
// 512 thr x 5 elems = 2560 slots; tail e in [2244,2560) lands at r<=38,
// ladr <= 38*72+65 = 2801 -- pad region; compute reads only < 33*72+66 = 2442.
constexpr int BPLANE = 2816;
constexpr int NW = CPG * K * K * OPG; // 576 combined weights per (b,g)

// ---------------- Kernel 1: per-(b,c) mean and 1/(std+eps) ----------------
__global__ __launch_bounds__(256) void stats_kernel(const float* __restrict__ x,
                                                    float2* __restrict__ stats) {
    int bc = blockIdx.x;                       // 0..B*C-1
    const float4* xv = (const float4*)(x + (size_t)bc * HW);
    int tid = threadIdx.x;
    float sum = 0.f, sumsq = 0.f;
#pragma unroll
    for (int it = 0; it < HW / 4 / 256; ++it) {  // 16 iters
        float4 v = xv[tid + it * 256];
        sum   += v.x + v.y + v.z + v.w;
        sumsq += v.x*v.x + v.y*v.y + v.z*v.z + v.w*v.w;
    }
#pragma unroll
    for (int off = 32; off > 0; off >>= 1) {
        sum   += __shfl_down(sum, off);
        sumsq += __shfl_down(sumsq, off);
    }
    __shared__ float s_sum[4], s_sq[4];
    int wave = tid >> 6;
    if ((tid & 63) == 0) { s_sum[wave] = sum; s_sq[wave] = sumsq; }
    __syncthreads();
    if (tid == 0) {
        float ts = s_sum[0] + s_sum[1] + s_sum[2] + s_sum[3];
        float tq = s_sq[0] + s_sq[1] + s_sq[2] + s_sq[3];
        float mean = ts / (float)HW;
        float var  = (tq - ts * ts / (float)HW) / (float)(HW - 1); // ddof=1
        var = fmaxf(var, 0.f);
        float stdv = sqrtf(var) + EPS;                             // eps on std, like torch
        stats[bc] = make_float2(mean, 1.0f / stdv);
    }
}

// ---------------- Kernel 2: fold 1x1 conv AND 1/std into 3x3 weights ----------------
// CW[b][g][i][ky][kx][o'] = istd_i * sum_j pw[b, g*OPG+o', j] * dw[b, g*OPG+j, i, ky, kx]
__global__ __launch_bounds__(256) void combine_kernel(const float* __restrict__ dw,
                                                      const float* __restrict__ pw,
                                                      const float2* __restrict__ stats,
                                                      float* __restrict__ cw) {
    int idx = blockIdx.x * 256 + threadIdx.x;   // exactly B*GROUPS*NW threads
    int o  = idx % OPG;  int t = idx / OPG;
    int kx = t % K;      t /= K;
    int ky = t % K;      t /= K;
    int i  = t % CPG;    t /= CPG;
    int g  = t % GROUPS; int b = t / GROUPS;
    const float* pwp = pw + (size_t)(b * O + g * OPG + o) * CPG;
    float acc = 0.f;
#pragma unroll
    for (int j = 0; j < CPG; ++j) {
        float wd = dw[(((size_t)(b * O + g * OPG + j) * CPG + i) * K + ky) * K + kx];
        acc = fmaf(pwp[j], wd, acc);
    }
    float istd = stats[b * C + g * CPG + i].y;
    cw[idx] = acc * istd;
}

// ---------------- Kernel 3: fused conv + bias ----------------
// Normalization folded into weights (1/std) and adjusted bias (mean term);
// OOB taps staged as mean so (m-m)*istd == 0 matches zero-padded normalized
// input. 512 threads cover a 64x32 tile; each thread: 4 px x all 8 outputs
// (32 acc chains -> deep ILP; round-0 measured this core at 88 VGPR).
// No o-split -> each sx row read once. Per-channel double-buffered pipeline:
// load(i+1)->regs, compute(i), write(i+1)->LDS, one barrier per channel.
__global__ __launch_bounds__(512, 4) void conv_kernel(const float* __restrict__ x,
                                                      const float* __restrict__ cw,
                                                      const float* __restrict__ bias,
                                                      const float2* __restrict__ stats,
                                                      float* __restrict__ out) {
    __shared__ float sw[NW];             // 2304 B
    __shared__ float sx[2][BPLANE];      // 22528 B
    __shared__ float sbias[OPG];         // 32 B

    int blk  = blockIdx.x;
    int tile = blk & 7;           // 8 supertiles per (b,g): 2 in x, 4 in y
    int g    = (blk >> 3) & 31;
    int b    = blk >> 8;
    int x0g  = (tile & 1) * TW;
    int y0g  = (tile >> 1) * TH;
    int tid  = threadIdx.x;

    // stage combined weights
    const float* cwp = cw + (size_t)(b * GROUPS + g) * NW;
    for (int e = tid; e < NW; e += NT) sw[e] = cwp[e];

    const float2* stp  = stats + b * C + g * CPG;
    const float* xbase = x + (size_t)(b * C + g * CPG) * HW;

    // i-invariant staging decode: 5 elements per thread covering 34x66 halo tile
    int ladr[5]; int gofs[5]; bool vm[5];
#pragma unroll
    for (int j = 0; j < 5; ++j) {
        int e = tid + j * NT;             // < 2560
        int r = e / HALOW;
        int c = e - r * HALOW;
        int gy = y0g + r - 1, gx = x0g + c - 1;
        bool v = (e < SELEM) && gy >= 0 && gy < H && gx >= 0 && gx < W;
        vm[j]   = v;
        gofs[j] = v ? gy * W + gx : 0;    // clamped: masked lanes read elem 0 (safe)
        ladr[j] = r * XSTR + c;           // tail lanes land in pad region of buffer
    }

    auto stage_load = [&](int i, float (&rv)[5]) {
        const float* xp = xbase + (size_t)i * HW;
#pragma unroll
        for (int j = 0; j < 5; ++j) rv[j] = xp[gofs[j]];
    };
    // select vs mean deferred to write time so the vmcnt wait lands late (T14)
    auto stage_write = [&](int i, float* dst, float (&rv)[5]) {
        float mi = stp[i].x;
#pragma unroll
        for (int j = 0; j < 5; ++j) dst[ladr[j]] = vm[j] ? rv[j] : mi;
    };

    // prologue: stage plane 0
    {
        float rv0[5];
        stage_load(0, rv0);
        stage_write(0, sx[0], rv0);
    }
    __syncthreads();

    // adjusted bias: sbias[o] = bias[o] - sum_{i,ky,kx} sw[i,ky,kx,o]*mean_i
    // wave 0 only (uniform branch), lane (o=tid&7, ii=tid>>3), shfl-reduce over ii
    if (tid < 64) {
        int o = tid & 7, ii = tid >> 3;
        float m = stp[ii].x;
        float p = 0.f;
#pragma unroll
        for (int t9 = 0; t9 < 9; ++t9) p += sw[(ii * 9 + t9) * OPG + o] * m;
#pragma unroll
        for (int d = 8; d < 64; d <<= 1) p += __shfl_xor(p, d);
        if (tid < OPG) sbias[tid] = bias[b * O + g * OPG + tid] - p;
    }

    // pixel mapping: 16 x-threads x 32 y-threads, 4 px each
    int xl = (tid & 15) * 4;     // local pixel x of first of 4 (0..60)
    int py = tid >> 4;           // local pixel y (0..31)

    float acc[OPG][4];
#pragma unroll
    for (int o = 0; o < OPG; ++o)
#pragma unroll
        for (int p = 0; p < 4; ++p) acc[o][p] = 0.f;

#pragma unroll 1
    for (int i = 0; i < CPG; ++i) {
        float rv[5];
        if (i + 1 < CPG) stage_load(i + 1, rv);   // loads in flight across compute

        const float* bufp = sx[i & 1];
#pragma unroll
        for (int ky = 0; ky < K; ++ky) {
            const float* rp = bufp + (py + ky) * XSTR + xl;
            float4 a  = *(const float4*)rp;        // 16B aligned
            float2 b2 = *(const float2*)(rp + 4);
            float xv[6] = {a.x, a.y, a.z, a.w, b2.x, b2.y};
#pragma unroll
            for (int kx = 0; kx < K; ++kx) {
                const float* wp = &sw[((i * K + ky) * K + kx) * OPG];
                float4 w0 = *(const float4*)wp;    // wave-uniform -> LDS broadcast
                float4 w1 = *(const float4*)(wp + 4);
                float wv[8] = {w0.x, w0.y, w0.z, w0.w, w1.x, w1.y, w1.z, w1.w};
#pragma unroll
                for (int o = 0; o < OPG; ++o)
#pragma unroll
                    for (int p = 0; p < 4; ++p)
                        acc[o][p] = fmaf(wv[o], xv[kx + p], acc[o][p]);
            }
        }

        if (i + 1 < CPG) stage_write(i + 1, sx[(i + 1) & 1], rv);
        __syncthreads();
    }

    // epilogue: add adjusted bias, store float4 per output channel
    int gy = y0g + py, gxs = x0g + xl;
    float* op = out + (((size_t)(b * O + g * OPG) * H + gy) * W + gxs);
#pragma unroll
    for (int o = 0; o < OPG; ++o) {
        float bv = sbias[o];
        float4 r = make_float4(acc[o][0] + bv, acc[o][1] + bv,
                               acc[o][2] + bv, acc[o][3] + bv);
        *(float4*)(op + (size_t)o * HW) = r;
    }
}

extern "C" void kernel_launch(void* const* d_in, const int* in_sizes, int n_in,
                              void* d_out, int out_size, void* d_ws, size_t ws_size,
                              hipStream_t stream) {
    const float* x    = (const float*)d_in[0];
    const float* dw   = (const float*)d_in[1];
    const float* pw   = (const float*)d_in[2];
    const float* bias = (const float*)d_in[3];
    float* out = (float*)d_out;

    // workspace layout: stats (B*C float2 = 32 KB), then combined weights (1.18 MB)
    float2* stats = (float2*)d_ws;
    float*  cwbuf = (float*)((char*)d_ws + B * C * sizeof(float2));

    stats_kernel<<<B * C, 256, 0, stream>>>(x, stats);
    combine_kernel<<<(B * GROUPS * NW) / 256, 256, 0, stream>>>(dw, pw, stats, cwbuf);
    conv_kernel<<<B * GROUPS * 8, NT, 0, stream>>>(x, cwbuf, bias, stats, out);
}